// Round 2
// baseline (145.654 us; speedup 1.0000x reference)
//
#include <hip/hip_runtime.h>
#include <stdint.h>

typedef __bf16 bf16_t;
typedef bf16_t bf16x8 __attribute__((ext_vector_type(8)));
typedef float f32x4 __attribute__((ext_vector_type(4)));
typedef uint32_t u32x4 __attribute__((ext_vector_type(4)));
typedef uint16_t u16x8 __attribute__((ext_vector_type(8)));

union FragU { u32x4 u; bf16x8 v; u16x8 s; };

__device__ __forceinline__ uint16_t f2bf_rne(float f) {
  uint32_t u = __float_as_uint(f);
  return (uint16_t)((u + 0x7fffu + ((u >> 16) & 1u)) >> 16);
}
__device__ __forceinline__ float bf2f_bits(uint16_t h) {
  return __uint_as_float(((uint32_t)h) << 16);
}

// ---------------------------------------------------------------------------
// Kernel 1: pack W (512x52 f32) into MFMA B-fragment layout, bf16 hi + lo.
// Fragment layout for mfma_f32_16x16x32_bf16 B operand:
//   lane l holds B[k][n] with n = nt*16 + (l&15), k = ks*32 + (l>>4)*8 + j,
//   j = 0..7 (8 contiguous k per lane). N padded 52 -> 64 with zeros.
// ws layout: wf_hi[4096] u32x4 (64 KB) then wf_lo[4096] u32x4 (64 KB).
// ---------------------------------------------------------------------------
__global__ __launch_bounds__(256) void pack_w_kernel(
    const float* __restrict__ W, u32x4* __restrict__ wf_hi,
    u32x4* __restrict__ wf_lo) {
  int idx = blockIdx.x * 256 + threadIdx.x;  // fragment index, 16*4*64 = 4096
  if (idx >= 4096) return;
  int lane = idx & 63;
  int nt   = (idx >> 6) & 3;
  int ks   = idx >> 8;
  int n  = nt * 16 + (lane & 15);
  int kb = ks * 32 + (lane >> 4) * 8;
  FragU hi, lo;
#pragma unroll
  for (int j = 0; j < 8; ++j) {
    float w = (n < 52) ? W[(kb + j) * 52 + n] : 0.0f;
    uint16_t h = f2bf_rne(w);
    hi.s[j] = h;
    lo.s[j] = f2bf_rne(w - bf2f_bits(h));
  }
  wf_hi[idx] = hi.u;
  wf_lo[idx] = lo.u;
}

#define MFMA16(a, b, c) __builtin_amdgcn_mfma_f32_16x16x32_bf16((a), (b), (c), 0, 0, 0)

// ---------------------------------------------------------------------------
// Kernel 2: fused GEMM (bf16 hi/lo split MFMA) + bias + softmax(13) + rule mix.
// Block = 256 threads = 4 waves; each wave owns 32 rows (2 M-tiles of 16).
// Block owns 128 rows. K = 512 in 16 steps of 32.
// ---------------------------------------------------------------------------
__global__ __launch_bounds__(256) void raven_main_kernel(
    const float* __restrict__ z, const float* __restrict__ xq,
    const u32x4* __restrict__ wfh, const u32x4* __restrict__ wfl,
    const float* __restrict__ bias, float* __restrict__ out) {
  __shared__ float lds[128][65];  // logits staging, stride 65 kills bank conflicts

  const int tid  = threadIdx.x;
  const int wave = tid >> 6;
  const int lane = tid & 63;
  const int r  = lane & 15;   // A-row within 16-tile / C col
  const int kg = lane >> 4;   // k-group (8 contiguous k per lane)

  const long long brow = (long long)blockIdx.x * 128;
  const long long wrow = brow + (long long)wave * 32;
  const float* zp0 = z + (wrow + r) * 512 + kg * 8;   // M-tile 0
  const float* zp1 = zp0 + 16 * 512;                  // M-tile 1

  f32x4 acc[2][4];
#pragma unroll
  for (int mt = 0; mt < 2; ++mt)
#pragma unroll
    for (int nt = 0; nt < 4; ++nt) {
      f32x4 zv = {0.0f, 0.0f, 0.0f, 0.0f};
      acc[mt][nt] = zv;
    }

#pragma unroll 2
  for (int ks = 0; ks < 16; ++ks) {
    // A: 8 f32 per lane per M-tile, contiguous k
    f32x4 a00 = *(const f32x4*)(zp0 + ks * 32);
    f32x4 a01 = *(const f32x4*)(zp0 + ks * 32 + 4);
    f32x4 a10 = *(const f32x4*)(zp1 + ks * 32);
    f32x4 a11 = *(const f32x4*)(zp1 + ks * 32 + 4);

    FragU h0, l0, h1, l1;
#pragma unroll
    for (int j = 0; j < 4; ++j) {
      { uint16_t hh = f2bf_rne(a00[j]); h0.s[j]     = hh; l0.s[j]     = f2bf_rne(a00[j] - bf2f_bits(hh)); }
      { uint16_t hh = f2bf_rne(a01[j]); h0.s[4 + j] = hh; l0.s[4 + j] = f2bf_rne(a01[j] - bf2f_bits(hh)); }
      { uint16_t hh = f2bf_rne(a10[j]); h1.s[j]     = hh; l1.s[j]     = f2bf_rne(a10[j] - bf2f_bits(hh)); }
      { uint16_t hh = f2bf_rne(a11[j]); h1.s[4 + j] = hh; l1.s[4 + j] = f2bf_rne(a11[j] - bf2f_bits(hh)); }
    }

    const u32x4* ph = wfh + ks * 256 + lane;
    const u32x4* pl = wfl + ks * 256 + lane;
#pragma unroll
    for (int nt = 0; nt < 4; ++nt) {
      FragU bh, bl;
      bh.u = ph[nt * 64];
      bl.u = pl[nt * 64];
      acc[0][nt] = MFMA16(h0.v, bh.v, acc[0][nt]);
      acc[1][nt] = MFMA16(h1.v, bh.v, acc[1][nt]);
      acc[0][nt] = MFMA16(l0.v, bh.v, acc[0][nt]);
      acc[1][nt] = MFMA16(l1.v, bh.v, acc[1][nt]);
      acc[0][nt] = MFMA16(h0.v, bl.v, acc[0][nt]);
      acc[1][nt] = MFMA16(h1.v, bl.v, acc[1][nt]);
    }
  }

  // C layout: col = lane&15, row = (lane>>4)*4 + i  [m89-verified]
#pragma unroll
  for (int mt = 0; mt < 2; ++mt)
#pragma unroll
    for (int nt = 0; nt < 4; ++nt)
#pragma unroll
      for (int i = 0; i < 4; ++i)
        lds[wave * 32 + mt * 16 + kg * 4 + i][nt * 16 + r] = acc[mt][nt][i];

  __syncthreads();

  // Epilogue: per (row, group) softmax over 13 logits + rule-weighted sum.
  // rules = [a, b-2, b-1, b+1, b+2, a-b, a+b, min, max, b+2, b+1, b-2, b-1]
  for (int task = tid; task < 128 * 4; task += 256) {
    int row = task >> 2;
    int g   = task & 3;
    long long grow = brow + row;
    float a  = xq[grow * 8 + g];
    float bq = xq[grow * 8 + 4 + g];
    float l[13];
    float m = -1e30f;
#pragma unroll
    for (int u = 0; u < 13; ++u) {
      l[u] = lds[row][g * 13 + u] + bias[g * 13 + u];
      m = fmaxf(m, l[u]);
    }
    float s = 0.0f;
#pragma unroll
    for (int u = 0; u < 13; ++u) {
      float e = __expf(l[u] - m);
      l[u] = e;
      s += e;
    }
    float num = a * l[0]
              + (bq - 2.0f) * (l[1] + l[11])
              + (bq - 1.0f) * (l[2] + l[12])
              + (bq + 1.0f) * (l[3] + l[10])
              + (bq + 2.0f) * (l[4] + l[9])
              + (a - bq) * l[5]
              + (a + bq) * l[6]
              + fminf(a, bq) * l[7]
              + fmaxf(a, bq) * l[8];
    out[grow * 4 + g] = num / s;
  }
}

extern "C" void kernel_launch(void* const* d_in, const int* in_sizes, int n_in,
                              void* d_out, int out_size, void* d_ws, size_t ws_size,
                              hipStream_t stream) {
  const float* z    = (const float*)d_in[0];  // (B, 512)
  const float* xq   = (const float*)d_in[1];  // (B, 2, 4)
  const float* W    = (const float*)d_in[2];  // (512, 52)
  const float* bias = (const float*)d_in[3];  // (52,)
  float* out = (float*)d_out;                 // (B, 1, 4)

  const int B = in_sizes[0] / 512;            // 262144

  u32x4* wf_hi = (u32x4*)d_ws;
  u32x4* wf_lo = wf_hi + 4096;

  hipLaunchKernelGGL(pack_w_kernel, dim3(16), dim3(256), 0, stream, W, wf_hi, wf_lo);

  const int blocks = B / 128;                 // 2048
  hipLaunchKernelGGL(raven_main_kernel, dim3(blocks), dim3(256), 0, stream,
                     z, xq, (const u32x4*)wf_hi, (const u32x4*)wf_lo, bias, out);
}

// Round 4
// 145.129 us; speedup vs baseline: 1.0036x; 1.0036x over previous
//
#include <hip/hip_runtime.h>
#include <stdint.h>

typedef __bf16 bf16_t;
typedef bf16_t bf16x8 __attribute__((ext_vector_type(8)));
typedef float f32x4 __attribute__((ext_vector_type(4)));
typedef uint32_t u32x4 __attribute__((ext_vector_type(4)));
typedef uint16_t u16x8 __attribute__((ext_vector_type(8)));

union FragU { u32x4 u; bf16x8 v; u16x8 s; };

__device__ __forceinline__ uint16_t f2bf_rne(float f) {
  uint32_t u = __float_as_uint(f);
  return (uint16_t)((u + 0x7fffu + ((u >> 16) & 1u)) >> 16);
}
__device__ __forceinline__ float bf2f_bits(uint16_t h) {
  return __uint_as_float(((uint32_t)h) << 16);
}

// ---------------------------------------------------------------------------
// Kernel 1: pack W (512x52 f32) into MFMA B-fragment layout, bf16 hi + lo.
// B-frag layout for mfma_f32_16x16x32_bf16: lane l holds B[k][n] with
// n = nt*16 + (l&15), k = ks*32 + (l>>4)*8 + j, j = 0..7. N padded 52->64.
// ws: wf_hi[4096] u32x4 (64 KB) then wf_lo[4096] u32x4 (64 KB).
// ---------------------------------------------------------------------------
__global__ __launch_bounds__(256) void pack_w_kernel(
    const float* __restrict__ W, u32x4* __restrict__ wf_hi,
    u32x4* __restrict__ wf_lo) {
  int idx = blockIdx.x * 256 + threadIdx.x;  // 16*4*64 = 4096 fragments
  if (idx >= 4096) return;
  int lane = idx & 63;
  int nt   = (idx >> 6) & 3;
  int ks   = idx >> 8;
  int n  = nt * 16 + (lane & 15);
  int kb = ks * 32 + (lane >> 4) * 8;
  FragU hi, lo;
#pragma unroll
  for (int j = 0; j < 8; ++j) {
    float w = (n < 52) ? W[(kb + j) * 52 + n] : 0.0f;
    uint16_t h = f2bf_rne(w);
    hi.s[j] = h;
    lo.s[j] = f2bf_rne(w - bf2f_bits(h));
  }
  wf_hi[idx] = hi.u;
  wf_lo[idx] = lo.u;
}

#define MFMA16(a, b, c) __builtin_amdgcn_mfma_f32_16x16x32_bf16((a), (b), (c), 0, 0, 0)

// ---------------------------------------------------------------------------
// Kernel 2: fused GEMM + bias + softmax(13) + rule mix.
// A = bf16(z) (hi only, native cvt); B = W split hi+lo (error ~0.002/logit).
// Block = 256 threads = 4 waves; wave owns 32 rows; block owns 128 rows.
// K = 512 in 16 steps of 32, explicit 1-deep register prefetch of A.
// LDS logits tile MUST have stride >= 64: the C-write stores all 64 padded
// columns (round-3 bug: stride 53 overflowed into the next row).
// ---------------------------------------------------------------------------
__global__ __launch_bounds__(256, 4) void raven_main_kernel(
    const float* __restrict__ z, const float* __restrict__ xq,
    const u32x4* __restrict__ wfh, const u32x4* __restrict__ wfl,
    const float* __restrict__ bias, float* __restrict__ out) {
  __shared__ float lds[128][65];   // 65-stride: fits all 64 cols + kills conflicts
  __shared__ float lds_bias[52];

  const int tid  = threadIdx.x;
  const int wave = tid >> 6;
  const int lane = tid & 63;
  const int r  = lane & 15;   // A row within 16-tile / C col
  const int kg = lane >> 4;   // k-group (8 contiguous k per lane)

  if (tid < 52) lds_bias[tid] = bias[tid];

  const long long brow = (long long)blockIdx.x * 128;
  const long long wrow = brow + (long long)wave * 32;
  const float* zp0 = z + (wrow + r) * 512 + kg * 8;   // M-tile 0
  const float* zp1 = zp0 + 16 * 512;                  // M-tile 1

  f32x4 acc[2][4];
#pragma unroll
  for (int mt = 0; mt < 2; ++mt)
#pragma unroll
    for (int nt = 0; nt < 4; ++nt) {
      f32x4 zv = {0.0f, 0.0f, 0.0f, 0.0f};
      acc[mt][nt] = zv;
    }

  // prologue: loads for ks=0 in flight
  f32x4 c00 = *(const f32x4*)(zp0);
  f32x4 c01 = *(const f32x4*)(zp0 + 4);
  f32x4 c10 = *(const f32x4*)(zp1);
  f32x4 c11 = *(const f32x4*)(zp1 + 4);

#pragma unroll
  for (int ks = 0; ks < 16; ++ks) {
    // issue next step's A loads before touching this step's values
    f32x4 n00, n01, n10, n11;
    if (ks < 15) {
      n00 = *(const f32x4*)(zp0 + (ks + 1) * 32);
      n01 = *(const f32x4*)(zp0 + (ks + 1) * 32 + 4);
      n10 = *(const f32x4*)(zp1 + (ks + 1) * 32);
      n11 = *(const f32x4*)(zp1 + (ks + 1) * 32 + 4);
    } else {
      n00 = c00; n01 = c01; n10 = c10; n11 = c11;
    }

    // native HW cvt (v_cvt_pk_bf16_f32), hi only for A
    FragU h0, h1;
#pragma unroll
    for (int j = 0; j < 4; ++j) {
      h0.v[j]     = (bf16_t)c00[j];
      h0.v[4 + j] = (bf16_t)c01[j];
      h1.v[j]     = (bf16_t)c10[j];
      h1.v[4 + j] = (bf16_t)c11[j];
    }

    const u32x4* ph = wfh + ks * 256 + lane;
    const u32x4* pl = wfl + ks * 256 + lane;
#pragma unroll
    for (int nt = 0; nt < 4; ++nt) {
      FragU bh, bl;
      bh.u = ph[nt * 64];
      bl.u = pl[nt * 64];
      acc[0][nt] = MFMA16(h0.v, bh.v, acc[0][nt]);
      acc[0][nt] = MFMA16(h0.v, bl.v, acc[0][nt]);
      acc[1][nt] = MFMA16(h1.v, bh.v, acc[1][nt]);
      acc[1][nt] = MFMA16(h1.v, bl.v, acc[1][nt]);
    }

    c00 = n00; c01 = n01; c10 = n10; c11 = n11;
  }

  // C layout: col = lane&15, row = (lane>>4)*4 + i  [m89-verified]
#pragma unroll
  for (int mt = 0; mt < 2; ++mt)
#pragma unroll
    for (int nt = 0; nt < 4; ++nt)
#pragma unroll
      for (int i = 0; i < 4; ++i)
        lds[wave * 32 + mt * 16 + kg * 4 + i][nt * 16 + r] = acc[mt][nt][i];

  __syncthreads();

  // Epilogue: per (row, group) softmax over 13 logits + rule-weighted sum.
  // rules = [a, b-2, b-1, b+1, b+2, a-b, a+b, min, max, b+2, b+1, b-2, b-1]
  for (int task = tid; task < 128 * 4; task += 256) {
    int row = task >> 2;
    int g   = task & 3;
    long long grow = brow + row;
    float a  = xq[grow * 8 + g];
    float bq = xq[grow * 8 + 4 + g];
    float l[13];
    float m = -1e30f;
#pragma unroll
    for (int u = 0; u < 13; ++u) {
      l[u] = lds[row][g * 13 + u] + lds_bias[g * 13 + u];
      m = fmaxf(m, l[u]);
    }
    float s = 0.0f;
#pragma unroll
    for (int u = 0; u < 13; ++u) {
      float e = __expf(l[u] - m);
      l[u] = e;
      s += e;
    }
    float num = a * l[0]
              + (bq - 2.0f) * (l[1] + l[11])
              + (bq - 1.0f) * (l[2] + l[12])
              + (bq + 1.0f) * (l[3] + l[10])
              + (bq + 2.0f) * (l[4] + l[9])
              + (a - bq) * l[5]
              + (a + bq) * l[6]
              + fminf(a, bq) * l[7]
              + fmaxf(a, bq) * l[8];
    out[grow * 4 + g] = num / s;
  }
}

extern "C" void kernel_launch(void* const* d_in, const int* in_sizes, int n_in,
                              void* d_out, int out_size, void* d_ws, size_t ws_size,
                              hipStream_t stream) {
  const float* z    = (const float*)d_in[0];  // (B, 512)
  const float* xq   = (const float*)d_in[1];  // (B, 2, 4)
  const float* W    = (const float*)d_in[2];  // (512, 52)
  const float* bias = (const float*)d_in[3];  // (52,)
  float* out = (float*)d_out;                 // (B, 1, 4)

  const int B = in_sizes[0] / 512;            // 262144

  u32x4* wf_hi = (u32x4*)d_ws;
  u32x4* wf_lo = wf_hi + 4096;

  hipLaunchKernelGGL(pack_w_kernel, dim3(16), dim3(256), 0, stream, W, wf_hi, wf_lo);

  const int blocks = B / 128;                 // 2048
  hipLaunchKernelGGL(raven_main_kernel, dim3(blocks), dim3(256), 0, stream,
                     z, xq, (const u32x4*)wf_hi, (const u32x4*)wf_lo, bias, out);
}

// Round 6
// 128.689 us; speedup vs baseline: 1.1318x; 1.1277x over previous
//
#include <hip/hip_runtime.h>
#include <stdint.h>

typedef __bf16 bf16_t;
typedef bf16_t bf16x8 __attribute__((ext_vector_type(8)));
typedef float f32x4 __attribute__((ext_vector_type(4)));
typedef uint32_t u32x4 __attribute__((ext_vector_type(4)));
typedef uint16_t u16x8 __attribute__((ext_vector_type(8)));

union FragU { u32x4 u; bf16x8 v; u16x8 s; };

__device__ __forceinline__ uint16_t f2bf_rne(float f) {
  uint32_t u = __float_as_uint(f);
  return (uint16_t)((u + 0x7fffu + ((u >> 16) & 1u)) >> 16);
}
__device__ __forceinline__ float bf2f_bits(uint16_t h) {
  return __uint_as_float(((uint32_t)h) << 16);
}

// ---------------------------------------------------------------------------
// Kernel 1: pack W (512x52 f32) into MFMA B-fragment layout, bf16 hi + lo.
// B-frag for mfma_f32_16x16x32_bf16: lane l holds B[k][n], n = nt*16+(l&15),
// k = ks*32 + (l>>4)*8 + j. N padded 52->64. ws: wf_hi[4096] + wf_lo[4096].
// ---------------------------------------------------------------------------
__global__ __launch_bounds__(256) void pack_w_kernel(
    const float* __restrict__ W, u32x4* __restrict__ wf_hi,
    u32x4* __restrict__ wf_lo) {
  int idx = blockIdx.x * 256 + threadIdx.x;
  if (idx >= 4096) return;
  int lane = idx & 63;
  int nt   = (idx >> 6) & 3;
  int ks   = idx >> 8;
  int n  = nt * 16 + (lane & 15);
  int kb = ks * 32 + (lane >> 4) * 8;
  FragU hi, lo;
#pragma unroll
  for (int j = 0; j < 8; ++j) {
    float w = (n < 52) ? W[(kb + j) * 52 + n] : 0.0f;
    uint16_t h = f2bf_rne(w);
    hi.s[j] = h;
    lo.s[j] = f2bf_rne(w - bf2f_bits(h));
  }
  wf_hi[idx] = hi.u;
  wf_lo[idx] = lo.u;
}

#define MFMA16(a, b, c) __builtin_amdgcn_mfma_f32_16x16x32_bf16((a), (b), (c), 0, 0, 0)

// ---------------------------------------------------------------------------
// Kernel 2: fused GEMM + bias + softmax(13) + rule mix.
// z staged via global_load_lds (coalesced 128B runs/row, linear LDS dest,
// source pre-swizzled col^=((row&7)<<4) per m173), wave-private double
// buffer, counted vmcnt(4) so next-chunk staging stays in flight.
// LDS union: staging [4 waves][2][4096 B] = 32 KB  /  logits[128][65] f32.
// ---------------------------------------------------------------------------
__global__ __launch_bounds__(256, 3) void raven_main_kernel(
    const float* __restrict__ z, const float* __restrict__ xq,
    const u32x4* __restrict__ wfh, const u32x4* __restrict__ wfl,
    const float* __restrict__ bias, float* __restrict__ out) {
  __shared__ __align__(16) unsigned char smem[33280];  // max(32768, 128*65*4)
  __shared__ float lds_bias[52];

  const int tid  = threadIdx.x;
  const int wave = tid >> 6;
  const int lane = tid & 63;
  const int r  = lane & 15;   // A row within 16-tile / C col
  const int kg = lane >> 4;   // k-group (8 contiguous k per lane)

  if (tid < 52) lds_bias[tid] = bias[tid];

  const long long brow = (long long)blockIdx.x * 128;
  const long long wrow = brow + (long long)wave * 32;
  const float* zb = z + wrow * 512;

  unsigned char* stg = smem + wave * 8192;  // [2][4096]

  // staging: lane covers bytes [(lane&7)*16, +16) of row (i*8 + (lane>>3)),
  // source col pre-swizzled by ^((row&7)<<4) = ^((lane>>3)<<4)
  const int rloc = lane >> 3;
  const int foff = 4 * ((lane & 7) ^ rloc);  // swizzled float offset in 32-float chunk

  f32x4 acc[2][4];
#pragma unroll
  for (int mt = 0; mt < 2; ++mt)
#pragma unroll
    for (int nt = 0; nt < 4; ++nt) {
      f32x4 zv = {0.0f, 0.0f, 0.0f, 0.0f};
      acc[mt][nt] = zv;
    }

#define STAGE_CHUNK(ks_, buf_)                                                  \
  {                                                                             \
    const float* g_ = zb + rloc * 512 + (ks_) * 32 + foff;                      \
    _Pragma("unroll")                                                           \
    for (int i_ = 0; i_ < 4; ++i_)                                              \
      __builtin_amdgcn_global_load_lds(                                         \
          (const __attribute__((address_space(1))) void*)(g_ + i_ * 8 * 512),   \
          (__attribute__((address_space(3))) void*)((buf_) + i_ * 1024),        \
          16, 0, 0);                                                            \
  }

  STAGE_CHUNK(0, stg);  // prologue: chunk 0 -> buf0

  const int swz = (r & 7) << 4;

#pragma unroll
  for (int ks = 0; ks < 16; ++ks) {
    unsigned char* cur = stg + (ks & 1) * 4096;
    unsigned char* nxt = stg + ((ks + 1) & 1) * 4096;

    // B-frag loads FIRST: in-order vmcnt retirement then lets vmcnt(4) wait
    // {cur staging + B} while leaving the 4 next-chunk staging ops in flight.
    FragU bh[4], bl[4];
    const u32x4* ph = wfh + ks * 256 + lane;
    const u32x4* pl = wfl + ks * 256 + lane;
#pragma unroll
    for (int nt = 0; nt < 4; ++nt) {
      bh[nt].u = ph[nt * 64];
      bl[nt].u = pl[nt * 64];
    }
    __builtin_amdgcn_sched_barrier(0);

    if (ks < 15) STAGE_CHUNK(ks + 1, nxt);
    __builtin_amdgcn_sched_barrier(0);
    if (ks < 15) asm volatile("s_waitcnt vmcnt(4)" ::: "memory");
    else         asm volatile("s_waitcnt vmcnt(0)" ::: "memory");
    __builtin_amdgcn_sched_barrier(0);

    // A-frags from LDS (swizzled ds_read_b128), convert to bf16
    const unsigned char* c0 = cur + r * 128;
    const unsigned char* c1 = cur + (r + 16) * 128;
    f32x4 a00 = *(const f32x4*)(c0 + ((kg * 32) ^ swz));
    f32x4 a01 = *(const f32x4*)(c0 + ((kg * 32 + 16) ^ swz));
    f32x4 a10 = *(const f32x4*)(c1 + ((kg * 32) ^ swz));
    f32x4 a11 = *(const f32x4*)(c1 + ((kg * 32 + 16) ^ swz));

    FragU h0, h1;
#pragma unroll
    for (int j = 0; j < 4; ++j) {
      h0.v[j]     = (bf16_t)a00[j];
      h0.v[4 + j] = (bf16_t)a01[j];
      h1.v[j]     = (bf16_t)a10[j];
      h1.v[4 + j] = (bf16_t)a11[j];
    }

#pragma unroll
    for (int nt = 0; nt < 4; ++nt) {
      acc[0][nt] = MFMA16(h0.v, bh[nt].v, acc[0][nt]);
      acc[0][nt] = MFMA16(h0.v, bl[nt].v, acc[0][nt]);
      acc[1][nt] = MFMA16(h1.v, bh[nt].v, acc[1][nt]);
      acc[1][nt] = MFMA16(h1.v, bl[nt].v, acc[1][nt]);
    }
  }
#undef STAGE_CHUNK

  // staging area is dead only after ALL waves finish their K-loop
  __syncthreads();

  float (*lds)[65] = (float(*)[65])smem;  // logits tile aliases staging

  // C layout: col = lane&15, row = (lane>>4)*4 + i  [m89-verified]
#pragma unroll
  for (int mt = 0; mt < 2; ++mt)
#pragma unroll
    for (int nt = 0; nt < 4; ++nt)
#pragma unroll
      for (int i = 0; i < 4; ++i)
        lds[wave * 32 + mt * 16 + kg * 4 + i][nt * 16 + r] = acc[mt][nt][i];

  __syncthreads();

  // Epilogue: per (row, group) softmax over 13 logits + rule-weighted sum.
  // rules = [a, b-2, b-1, b+1, b+2, a-b, a+b, min, max, b+2, b+1, b-2, b-1]
  for (int task = tid; task < 128 * 4; task += 256) {
    int row = task >> 2;
    int g   = task & 3;
    long long grow = brow + row;
    float a  = xq[grow * 8 + g];
    float bq = xq[grow * 8 + 4 + g];
    float l[13];
    float m = -1e30f;
#pragma unroll
    for (int u = 0; u < 13; ++u) {
      l[u] = lds[row][g * 13 + u] + lds_bias[g * 13 + u];
      m = fmaxf(m, l[u]);
    }
    float s = 0.0f;
#pragma unroll
    for (int u = 0; u < 13; ++u) {
      float e = __expf(l[u] - m);
      l[u] = e;
      s += e;
    }
    float num = a * l[0]
              + (bq - 2.0f) * (l[1] + l[11])
              + (bq - 1.0f) * (l[2] + l[12])
              + (bq + 1.0f) * (l[3] + l[10])
              + (bq + 2.0f) * (l[4] + l[9])
              + (a - bq) * l[5]
              + (a + bq) * l[6]
              + fminf(a, bq) * l[7]
              + fmaxf(a, bq) * l[8];
    out[grow * 4 + g] = num / s;
  }
}

extern "C" void kernel_launch(void* const* d_in, const int* in_sizes, int n_in,
                              void* d_out, int out_size, void* d_ws, size_t ws_size,
                              hipStream_t stream) {
  const float* z    = (const float*)d_in[0];  // (B, 512)
  const float* xq   = (const float*)d_in[1];  // (B, 2, 4)
  const float* W    = (const float*)d_in[2];  // (512, 52)
  const float* bias = (const float*)d_in[3];  // (52,)
  float* out = (float*)d_out;                 // (B, 1, 4)

  const int B = in_sizes[0] / 512;            // 262144

  u32x4* wf_hi = (u32x4*)d_ws;
  u32x4* wf_lo = wf_hi + 4096;

  hipLaunchKernelGGL(pack_w_kernel, dim3(16), dim3(256), 0, stream, W, wf_hi, wf_lo);

  const int blocks = B / 128;                 // 2048
  hipLaunchKernelGGL(raven_main_kernel, dim3(blocks), dim3(256), 0, stream,
                     z, xq, (const u32x4*)wf_hi, (const u32x4*)wf_lo, bias, out);
}